// Round 11
// baseline (4723.870 us; speedup 1.0000x reference)
//
#include <hip/hip_runtime.h>
#include <stdint.h>
#include <stddef.h>

// LSTM_63488206569533: B=128, T=1024, I=256, H=512, fp32 in/out.
// Persistent kernel: 256 WGs (8 batch-groups x 32 unit-slices), one per CU.
// R13 = R12 (wave-granular publication) with a LAUNCHER BUG FIXED:
//   flags is [2][PM][PN][4] = 8 KB but R12's memset only zeroed 4 KB --
//   odd-parity flags started as garbage -> spurious poll passes -> stale h.
//   Kernel body is R12 verbatim:
//  - vmcnt is per-wave HW state, so each wave drains ITS OWN h-store acks
//    (s_waitcnt vmcnt(0)) and posts ITS OWN flag -- no WG-wide
//    __syncthreads() drain, no barrier convergence on the slowest thread.
//  - Consumer: thread tid's 8 u64s all come from slice (tid&127)>>2, so it
//    polls ONLY that slice's 4-flag quad (two u64 loads/round); data loads
//    still issued strictly AFTER flag-confirm (the staleness-proof order).
//  Safety: a wave posting flag=t has (program order) finished its step t-1
//  reads of the parity buffer being overwritten at step t -> the flag's
//  double duty (publication + reuse-safety) holds at wave granularity.

#define Bn   128
#define Tn   1024
#define In   256
#define Hn   512
#define PM   8     // batch groups
#define PN   32    // unit slices
#define BPW  16    // batches per WG
#define UPW  16    // units per WG
#define APAD 792   // padded A row len in bf16 (1584B)
#define GPAD 17    // gate_lds padded row stride

typedef float f4 __attribute__((ext_vector_type(4)));
typedef short s8 __attribute__((ext_vector_type(8)));
typedef unsigned long long u64;

// LDS-ordering barrier WITHOUT the vmcnt(0) drain __syncthreads would emit.
#define SBAR() do {                                        \
    __builtin_amdgcn_sched_barrier(0);                     \
    asm volatile("s_waitcnt lgkmcnt(0)" ::: "memory");     \
    __builtin_amdgcn_s_barrier();                          \
    __builtin_amdgcn_sched_barrier(0);                     \
  } while (0)

static __device__ __forceinline__ short f2bf(float f) {
  union { float f; unsigned u; } v; v.f = f;
  unsigned u = v.u;
  return (short)((u + 0x7FFFu + ((u >> 16) & 1u)) >> 16);  // RNE
}

__global__ __launch_bounds__(256, 1)
void lstm_persist(const float* __restrict__ x,
                  const float* __restrict__ W_ih,
                  const float* __restrict__ W_hh,
                  const float* __restrict__ b_ih,
                  const float* __restrict__ b_hh,
                  const float* __restrict__ fc_w,
                  const float* __restrict__ fc_b,
                  float* __restrict__ out,
                  short* __restrict__ hbuf,      // [2][Bn][Hn] bf16 bits
                  unsigned* __restrict__ flags)  // [2][PM][PN][4] wave flags
{
  const int tid  = threadIdx.x;
  const int wave = tid >> 6;    // 0..3  == gate type (i,f,g,o)
  const int lane = tid & 63;
  const int n16  = lane & 15;   // MFMA: batch row (A) / gate col (B)
  const int q    = lane >> 4;   // MFMA quad -> k-subblock
  const int bg   = blockIdx.x & 7;   // batch group
  const int ns   = blockIdx.x >> 3;  // unit slice 0..31

  __shared__ short A_lds[16 * APAD];       // [batch 16][k 768(+pad)] bf16
  __shared__ float gate_lds[4 * 16 * GPAD];

  // ---- one-time: preload this wave's 16 W rows into B-fragments (bf16) ----
  s8 bfrag[24];
  {
    const int grow = wave * Hn + ns * UPW + n16;  // global gate row in [0,4H)
#pragma unroll
    for (int kk = 0; kk < 24; ++kk) {
      const float* p = (kk < 8)
        ? (W_ih + (size_t)grow * In + kk * 32 + q * 8)
        : (W_hh + (size_t)grow * Hn + (kk - 8) * 32 + q * 8);
      f4 lo = ((const f4*)p)[0];
      f4 hi = ((const f4*)p)[1];
      s8 b;
      b[0]=f2bf(lo[0]); b[1]=f2bf(lo[1]); b[2]=f2bf(lo[2]); b[3]=f2bf(lo[3]);
      b[4]=f2bf(hi[0]); b[5]=f2bf(hi[1]); b[6]=f2bf(hi[2]); b[7]=f2bf(hi[3]);
      bfrag[kk] = b;
    }
  }

  // ---- elementwise-phase mapping: tid -> (batch em, unit en) ----
  const int em  = tid >> 4;
  const int en  = tid & 15;
  const int ug  = ns * UPW + en;     // global unit
  const int bgl = bg * BPW + em;     // global batch
  const float bia = b_ih[ug]        + b_hh[ug];
  const float bfa = b_ih[Hn + ug]   + b_hh[Hn + ug];
  const float bga = b_ih[2*Hn + ug] + b_hh[2*Hn + ug];
  const float boa = b_ih[3*Hn + ug] + b_hh[3*Hn + ug];

  const float* xbase = x + (size_t)bgl * Tn * In + en * 16;
  const short* aptr  = A_lds + n16 * APAD + q * 8;
  const u64*   hb64  = (const u64*)hbuf;
  const int    psl   = (tid & 127) >> 2;   // producer slice of my 8 u64s

  // ---- prologue: stage x(0) ----
  {
    const f4* xp = (const f4*)xbase;
    f4 a = xp[0], b = xp[1], c = xp[2], d = xp[3];
    s8 lo, hi;
    lo[0]=f2bf(a[0]); lo[1]=f2bf(a[1]); lo[2]=f2bf(a[2]); lo[3]=f2bf(a[3]);
    lo[4]=f2bf(b[0]); lo[5]=f2bf(b[1]); lo[6]=f2bf(b[2]); lo[7]=f2bf(b[3]);
    hi[0]=f2bf(c[0]); hi[1]=f2bf(c[1]); hi[2]=f2bf(c[2]); hi[3]=f2bf(c[3]);
    hi[4]=f2bf(d[0]); hi[5]=f2bf(d[1]); hi[6]=f2bf(d[2]); hi[7]=f2bf(d[3]);
    s8* dst = (s8*)(A_lds + em * APAD + en * 16);
    dst[0] = lo; dst[1] = hi;
  }

  float creg = 0.f, hreg = 0.f;
  __syncthreads();   // once, full semantics

  for (int t = 0; t < Tn; ++t) {
    // (1) prefetch x(t+1) into registers (consumed at step (7))
    const int tn = (t + 1 < Tn) ? (t + 1) : t;
    const f4* xp = (const f4*)(xbase + (size_t)tn * In);
    f4 xa = xp[0], xb = xp[1], xc = xp[2], xd = xp[3];

    // (2) x-part MFMAs from A_lds (overlaps peers' flag propagation)
    f4 acc = {0.f, 0.f, 0.f, 0.f};
#pragma unroll
    for (int kk = 0; kk < 8; ++kk) {
      s8 a = *(const s8*)(aptr + kk * 32);
      acc = __builtin_amdgcn_mfma_f32_16x16x32_bf16(a, bfrag[kk], acc, 0, 0, 0);
    }

    if (t > 0) {
      // (3) per-thread flag poll: my producer slice's 4 wave-flags
      //     (two u64 loads/round). Wave proceeds when ITS 16 slices are up.
      {
        const unsigned want = (unsigned)t;
        const u64* fq = (const u64*)(flags + ((t & 1) * PM + bg) * (PN * 4) + psl * 4);
        for (;;) {
          u64 a0 = __hip_atomic_load(fq + 0, __ATOMIC_RELAXED, __HIP_MEMORY_SCOPE_AGENT);
          u64 a1 = __hip_atomic_load(fq + 1, __ATOMIC_RELAXED, __HIP_MEMORY_SCOPE_AGENT);
          if ((unsigned)a0 >= want && (unsigned)(a0 >> 32) >= want &&
              (unsigned)a1 >= want && (unsigned)(a1 >> 32) >= want) break;
        }
      }
      // (4) bulk h load (fresh: flags follow data): 8 coalesced u64/thread;
      //     u64 n = i*256+tid -> batch 2i+(tid>>7), units 4*(tid&127)..+3.
      const u64* pb = hb64 + (size_t)(t & 1) * (Bn * Hn / 4) + bg * (BPW * Hn / 4) + tid;
      u64 vals[8];
#pragma unroll
      for (int i = 0; i < 8; ++i)
        vals[i] = __hip_atomic_load(pb + i * 256, __ATOMIC_RELAXED,
                                    __HIP_MEMORY_SCOPE_AGENT);
      const int rbase = (tid >> 7);
      const int cshort = 256 + 4 * (tid & 127);
#pragma unroll
      for (int i = 0; i < 8; ++i)
        *(u64*)(A_lds + (2 * i + rbase) * APAD + cshort) = vals[i];
    }
    SBAR();   // (A) h staged; x(t) LDS reads complete

    if (t > 0) {
      // (5) h-part MFMAs
#pragma unroll
      for (int kk = 8; kk < 24; ++kk) {
        s8 a = *(const s8*)(aptr + kk * 32);
        acc = __builtin_amdgcn_mfma_f32_16x16x32_bf16(a, bfrag[kk], acc, 0, 0, 0);
      }
    }

    // (7) stage x(t+1) -> A_lds cols [0,256) (x(t) reads done before (A))
    {
      s8 lo, hi;
      lo[0]=f2bf(xa[0]); lo[1]=f2bf(xa[1]); lo[2]=f2bf(xa[2]); lo[3]=f2bf(xa[3]);
      lo[4]=f2bf(xb[0]); lo[5]=f2bf(xb[1]); lo[6]=f2bf(xb[2]); lo[7]=f2bf(xb[3]);
      hi[0]=f2bf(xc[0]); hi[1]=f2bf(xc[1]); hi[2]=f2bf(xc[2]); hi[3]=f2bf(xc[3]);
      hi[4]=f2bf(xd[0]); hi[5]=f2bf(xd[1]); hi[6]=f2bf(xd[2]); hi[7]=f2bf(xd[3]);
      s8* dst = (s8*)(A_lds + em * APAD + en * 16);
      dst[0] = lo; dst[1] = hi;
    }

    // (8) exchange gates through LDS (C-layout: row=(q*4+r)=batch, col=n16=unit)
#pragma unroll
    for (int r = 0; r < 4; ++r)
      gate_lds[wave * (16 * GPAD) + (q * 4 + r) * GPAD + n16] = acc[r];
    SBAR();   // (B) gates ready; x(t+1) staged

    // (9) per-(batch,unit) LSTM cell update; c stays in a register
    {
      float zi = gate_lds[0 * (16 * GPAD) + em * GPAD + en] + bia;
      float zf = gate_lds[1 * (16 * GPAD) + em * GPAD + en] + bfa;
      float zg = gate_lds[2 * (16 * GPAD) + em * GPAD + en] + bga;
      float zo = gate_lds[3 * (16 * GPAD) + em * GPAD + en] + boa;
      float gi = 1.f / (1.f + __expf(-zi));
      float gf = 1.f / (1.f + __expf(-zf));
      float gg = 2.f / (1.f + __expf(-2.f * zg)) - 1.f;   // tanh
      float go = 1.f / (1.f + __expf(-zo));
      creg = gf * creg + gi * gg;
      float tc = 2.f / (1.f + __expf(-2.f * creg)) - 1.f; // tanh(c)
      hreg = go * tc;
    }

    if (t + 1 < Tn) {
      // (10) store h(t+1) packed bf16 (2 units/dword; wave w covers batches
      //      bg*16+4w..+3, all 16 units)
      unsigned hb = (unsigned short)f2bf(hreg);
      unsigned ob = (unsigned)__shfl_xor((int)hb, 1, 64);
      if (!(en & 1)) {
        unsigned packed = hb | (ob << 16);
        unsigned* hp = (unsigned*)hbuf + (size_t)((t + 1) & 1) * (Bn * Hn / 2)
                     + bgl * (Hn / 2) + ((unsigned)ug >> 1);
        __hip_atomic_store(hp, packed, __ATOMIC_RELAXED, __HIP_MEMORY_SCOPE_AGENT);
      }
      // (11) WAVE-granular publication: drain THIS wave's store acks
      //      (vmcnt is per-wave), then lane 0 posts this wave's flag.
      __builtin_amdgcn_sched_barrier(0);
      asm volatile("s_waitcnt vmcnt(0)" ::: "memory");
      __builtin_amdgcn_sched_barrier(0);
      if (lane == 0)
        __hip_atomic_store(flags + (((t + 1) & 1) * PM + bg) * (PN * 4) + ns * 4 + wave,
                           (unsigned)(t + 1), __ATOMIC_RELAXED,
                           __HIP_MEMORY_SCOPE_AGENT);
    }
  }

  // ---- epilogue: out[b] = sum_u hT[b,u] * fc_w[u] + fc_b ----
  float partial = hreg * fc_w[ug];
#pragma unroll
  for (int off = 1; off < 16; off <<= 1)
    partial += __shfl_xor(partial, off, 64);   // reduce over the 16 units
  if (en == 0) {
    if (ns == 0) partial += fc_b[0];           // fc_b exactly once per batch
    atomicAdd(&out[bgl], partial);
  }
}

extern "C" void kernel_launch(void* const* d_in, const int* in_sizes, int n_in,
                              void* d_out, int out_size, void* d_ws, size_t ws_size,
                              hipStream_t stream) {
  const float* x    = (const float*)d_in[0];
  const float* W_ih = (const float*)d_in[1];
  const float* W_hh = (const float*)d_in[2];
  const float* b_ih = (const float*)d_in[3];
  const float* b_hh = (const float*)d_in[4];
  const float* fc_w = (const float*)d_in[5];
  const float* fc_b = (const float*)d_in[6];
  float* out = (float*)d_out;

  short*    hbuf  = (short*)d_ws;                          // 256 KB
  unsigned* flags = (unsigned*)((char*)d_ws + 262144);     // 8 KB (FIXED)

  // zero h + the FULL flag array every launch (R12 under-zeroed: 4 KB of an
  // 8 KB [2][PM][PN][4] array -> garbage odd-parity flags -> stale reads)
  hipMemsetAsync(d_ws, 0, 262144 + 8192, stream);
  hipMemsetAsync(d_out, 0, Bn * sizeof(float), stream);  // out via atomics

  lstm_persist<<<dim3(PM * PN), dim3(256), 0, stream>>>(
      x, W_ih, W_hh, b_ih, b_hh, fc_w, fc_b, out, hbuf, flags);
}